// Round 10
// baseline (140.654 us; speedup 1.0000x reference)
//
#include <hip/hip_runtime.h>
#include <math.h>

#define NBLK 784
#define PS 20                     // padded LDS row stride for P (floats)
#define LOG2PI_16 29.406033062549525f   // 16*log(2*pi)

// reduce buffer: Red[j*256 + g*32 + o], j = 0..32 (S1[0..15], S2[0..15], rs)
#define REDN (33 * 256)

// DPP cross-lane move (all lanes active; row-confined controls only)
#define DPPF(x, ctrl) __int_as_float(__builtin_amdgcn_update_dpp(              \
    0, __float_as_int(x), ctrl, 0xF, 0xF, true))

__device__ __forceinline__ float swzx16(float x) {   // lane ^= 16 (within 32)
    return __int_as_float(__builtin_amdgcn_ds_swizzle(__float_as_int(x), 0x401F));
}
// reduce over the 32 lanes of a half-wave (o dimension)
__device__ __forceinline__ float rmax32(float x) {
    x = fmaxf(x, DPPF(x, 0xB1));   // quad_perm 1,0,3,2
    x = fmaxf(x, DPPF(x, 0x4E));   // quad_perm 2,3,0,1
    x = fmaxf(x, DPPF(x, 0x141));  // row_half_mirror (pairs quads in 8)
    x = fmaxf(x, DPPF(x, 0x140));  // row_mirror (pairs 8-groups in 16)
    x = fmaxf(x, swzx16(x));       // pairs 16-groups in 32
    return x;
}
__device__ __forceinline__ float rsum32(float x) {
    x += DPPF(x, 0xB1);
    x += DPPF(x, 0x4E);
    x += DPPF(x, 0x141);
    x += DPPF(x, 0x140);
    x += swzx16(x);
    return x;
}

// votes for (o, n = g + 8k): v[16] = P[n] (4x4) * K[o][n] (4x4)
#define VOTE(kk, v) do {                                                       \
        float pv[16], kv[16];                                                  \
        const float4* Pp_ = (const float4*)(Pbase + (kk) * (8 * PS));          \
        ((float4*)pv)[0] = Pp_[0]; ((float4*)pv)[1] = Pp_[1];                  \
        ((float4*)pv)[2] = Pp_[2]; ((float4*)pv)[3] = Pp_[3];                  \
        const float4* Kp_ = (const float4*)(Kg + (kk) * (8 * 16));             \
        ((float4*)kv)[0] = Kp_[0]; ((float4*)kv)[1] = Kp_[1];                  \
        ((float4*)kv)[2] = Kp_[2]; ((float4*)kv)[3] = Kp_[3];                  \
        _Pragma("unroll")                                                      \
        for (int i_ = 0; i_ < 4; ++i_) {                                       \
            _Pragma("unroll")                                                  \
            for (int l_ = 0; l_ < 4; ++l_) {                                   \
                v[i_*4+l_] = fmaf(pv[i_*4+0], kv[0+l_],                        \
                             fmaf(pv[i_*4+1], kv[4+l_],                        \
                             fmaf(pv[i_*4+2], kv[8+l_],                        \
                                  pv[i_*4+3] * kv[12+l_])));                   \
            }                                                                  \
        }                                                                      \
    } while (0)

// cross-wave reduce of S1/S2/rs over the 8 g's (SoA layout, conflict-free b32)
#define REDUCE_G() do {                                                        \
    __syncthreads();                                                           \
    _Pragma("unroll")                                                          \
    for (int j = 0; j < 16; ++j) {                                             \
        Red[j * 256 + t]        = S1[j];                                       \
        Red[(j + 16) * 256 + t] = S2[j];                                       \
    }                                                                          \
    Red[32 * 256 + t] = rs;                                                    \
    __syncthreads();                                                           \
    _Pragma("unroll")                                                          \
    for (int j = 0; j < 16; ++j) { S1[j] = 0.f; S2[j] = 0.f; }                 \
    rs = 0.f;                                                                  \
    _Pragma("unroll")                                                          \
    for (int gg = 0; gg < 8; ++gg) {                                           \
        const int base_ = gg * 32 + o;                                         \
        _Pragma("unroll")                                                      \
        for (int j = 0; j < 16; ++j) {                                         \
            S1[j] += Red[j * 256 + base_];                                     \
            S2[j] += Red[(j + 16) * 256 + base_];                              \
        }                                                                      \
        rs += Red[32 * 256 + base_];                                           \
    }                                                                          \
} while (0)

// moments -> mu, sig, L, a_out (redundant per lane; all static indexing)
#define STATS(IT) do {                                                         \
    rs += 1e-9f;                                                               \
    const float ivr_ = 1.0f / rs;                                              \
    _Pragma("unroll")                                                          \
    for (int j = 0; j < 16; ++j) {                                             \
        mu[j]  = S1[j] * ivr_;                                                 \
        sig[j] = fmaf(-mu[j], mu[j], S2[j] * ivr_) + 1e-9f;                    \
    }                                                                          \
    L = __logf(sig[0]  * sig[1])  + __logf(sig[2]  * sig[3])                   \
      + __logf(sig[4]  * sig[5])  + __logf(sig[6]  * sig[7])                   \
      + __logf(sig[8]  * sig[9])  + __logf(sig[10] * sig[11])                  \
      + __logf(sig[12] * sig[13]) + __logf(sig[14] * sig[15]);                 \
    const float cost_ = rs * fmaf(0.5f, L, 16.0f * buv);                       \
    a_out = 1.0f / (1.0f + __expf(-(IT) * (ba - cost_)));                      \
} while (0)

// prep logit constants for the NEXT fused pass
#define PREP() do {                                                            \
    float c0_ = 0.f;                                                           \
    _Pragma("unroll")                                                          \
    for (int j = 0; j < 16; ++j) {                                             \
        isg[j] = 1.0f / sig[j];                                                \
        qb[j]  = -2.0f * mu[j] * isg[j];                                       \
        c0_    = fmaf(mu[j] * mu[j], isg[j], c0_);                             \
    }                                                                          \
    LC = __logf(a_out + 1e-9f) - 0.5f * (LOG2PI_16 + L) - 0.5f * c0_;          \
} while (0)

__global__ __launch_bounds__(256) void convcaps_em(
    const float* __restrict__ poses,
    const float* __restrict__ acts,
    const float* __restrict__ kern,
    const float* __restrict__ beta_a,
    const float* __restrict__ beta_u,
    float* __restrict__ out)
{
    const int pix = blockIdx.x;          // b*196 + ho*14 + wo
    const int b  = pix / 196;
    const int hw = pix - b * 196;
    const int ho = hw / 14;
    const int wo = hw - ho * 14;

    __shared__ __align__(16) float P[144 * PS];
    __shared__ float A[144];
    __shared__ float Red[REDN];

    const int t = threadIdx.x;

    // ---- stage pose block + activations
    for (int idx = t; idx < 144 * 16; idx += 256) {
        int n = idx >> 4, d = idx & 15;
        int ki = n / 48, kj = (n >> 4) - ki * 3, c = n & 15;
        P[n * PS + d] = poses[((b * 16 + ho + ki) * 16 + (wo + kj)) * 256 + c * 16 + d];
    }
    if (t < 144) {
        int n = t;
        int ki = n / 48, kj = (n >> 4) - ki * 3, c = n & 15;
        A[n] = acts[((b * 16 + ho + ki) * 16 + (wo + kj)) * 16 + c];
    }
    __syncthreads();

    const int o = t & 31;                // capsule (32, within half-wave)
    const int g = t >> 5;                // n-slice (8, spans 4 waves)
    const float buv = beta_u[o];
    const float ba  = beta_a[o];
    const float* Kbase = kern + (size_t)o * 2304;   // 144*16
    const float* Pbase = P + g * PS;
    const float* Kg    = Kbase + g * 16;

    float S1[16], S2[16], rs;
    float mu[16], sig[16], isg[16], qb[16];
    float L, LC = 0.f, a_out = 0.f;

    // ===== iter 0: r = A[n]/32 (uniform R), no softmax =====
#pragma unroll
    for (int j = 0; j < 16; ++j) { S1[j] = 0.f; S2[j] = 0.f; }
    rs = 0.f;
#pragma unroll 3
    for (int k = 0; k < 18; ++k) {
        float v[16];
        VOTE(k, v);
        const float r = A[g + (k << 3)] * 0.03125f;
        rs += r;
#pragma unroll
        for (int j = 0; j < 16; ++j) {
            S1[j] = fmaf(r, v[j], S1[j]);
            S2[j] = fmaf(r * v[j], v[j], S2[j]);
        }
    }
    REDUCE_G();
    STATS(1.0f);
    PREP();

    // ===== iters 1,2: fused logits -> in-wave softmax -> moments =====
#pragma unroll 1
    for (int it = 1; it < 3; ++it) {
#pragma unroll
        for (int j = 0; j < 16; ++j) { S1[j] = 0.f; S2[j] = 0.f; }
        rs = 0.f;
#pragma unroll 2
        for (int k = 0; k < 18; ++k) {
            float v[16];
            VOTE(k, v);
            float Q = 0.f;
#pragma unroll
            for (int j = 0; j < 16; ++j)
                Q = fmaf(fmaf(isg[j], v[j], qb[j]), v[j], Q);
            const float lg = fmaf(-0.5f, Q, LC);
            const float mx = rmax32(lg);             // softmax over o, in-wave
            const float e  = __expf(lg - mx);
            const float sm = rsum32(e);
            float inv_sm;
            asm("v_rcp_f32 %0, %1" : "=v"(inv_sm) : "v"(sm));
            const float r = e * A[g + (k << 3)] * inv_sm;   // R * a_in
            rs += r;
#pragma unroll
            for (int j = 0; j < 16; ++j) {
                S1[j] = fmaf(r, v[j], S1[j]);
                S2[j] = fmaf(r * v[j], v[j], S2[j]);
            }
        }
        REDUCE_G();
        STATS((float)(it + 1));
        if (it < 2) PREP();
    }

    // ===== outputs: poses [pix][o][16], activations [pix][o] =====
    if (g == 0) {
        float4* ob = (float4*)(out + (size_t)pix * 512 + o * 16);
        ob[0] = make_float4(mu[0],  mu[1],  mu[2],  mu[3]);
        ob[1] = make_float4(mu[4],  mu[5],  mu[6],  mu[7]);
        ob[2] = make_float4(mu[8],  mu[9],  mu[10], mu[11]);
        ob[3] = make_float4(mu[12], mu[13], mu[14], mu[15]);
        out[401408 + pix * 32 + o] = a_out;
    }
}

extern "C" void kernel_launch(void* const* d_in, const int* in_sizes, int n_in,
                              void* d_out, int out_size, void* d_ws, size_t ws_size,
                              hipStream_t stream)
{
    const float* poses  = (const float*)d_in[0];
    const float* acts   = (const float*)d_in[1];
    const float* kern   = (const float*)d_in[2];
    const float* beta_a = (const float*)d_in[3];
    const float* beta_u = (const float*)d_in[4];
    float* out = (float*)d_out;
    convcaps_em<<<NBLK, 256, 0, stream>>>(poses, acts, kern, beta_a, beta_u, out);
}